// Round 5
// baseline (383.491 us; speedup 1.0000x reference)
//
#include <hip/hip_runtime.h>

#define NN 50000
#define EE 800000
#define D  128
#define SBLK 49        // ceil(NN/1024) for scan
#define HT_BITS 13
#define HT_SIZE 8192   // nodes per histogram tile
#define HT_TILES 7     // ceil(NN/HT_SIZE)
#define HT_BPT 32      // blocks per tile

typedef short short8 __attribute__((ext_vector_type(8)));
typedef float floatx4 __attribute__((ext_vector_type(4)));

__device__ __forceinline__ float leaky(float v) { return v > 0.f ? v : 0.01f * v; }

__device__ __forceinline__ unsigned short f2bf(float f) {
    unsigned int u = __float_as_uint(f);
    u = (u + 0x7fff + ((u >> 16) & 1)) >> 16;     // round-to-nearest-even
    return (unsigned short)u;
}
__device__ __forceinline__ float bf2f(unsigned int h) {
    return __uint_as_float(h << 16);
}

// ------------- pack 6 weight mats into bf16 B-fragment order -------------
__global__ void k_pack(const float* __restrict__ Wp,  const float* __restrict__ Wc0,
                       const float* __restrict__ Wc1, const float* __restrict__ Wrel,
                       const float* __restrict__ Wroot, const float* __restrict__ Wl,
                       unsigned short* __restrict__ Pall) {
    int gid = blockIdx.x * blockDim.x + threadIdx.x;
    if (gid >= 6 * 16384) return;
    int m = gid >> 14;
    int r = gid & 16383;
    int j  = r & 7;
    int l  = (r >> 3) & 63;
    int ct = (r >> 9) & 7;
    int kc = r >> 12;
    int n = ct * 16 + (l & 15);
    int k = kc * 32 + (l >> 4) * 8 + j;
    const float* W = m == 0 ? Wp : m == 1 ? Wc0 : m == 2 ? Wc1
                   : m == 3 ? Wrel : m == 4 ? Wroot : Wl;
    Pall[gid] = f2bf(W[n * 128 + k]);
}

// ------------- tiled LDS histogram: weighted out-degree (src) + in-degree (dst) -------------
// No global atomics: each block owns (tile, edge-slice), accumulates in LDS,
// writes its 8192-entry partials non-atomically to scratch.
__global__ __launch_bounds__(256) void k_hist(const int* __restrict__ src,
                                              const int* __restrict__ dst,
                                              const float* __restrict__ ew,
                                              float* __restrict__ part_deg,
                                              int* __restrict__ part_cnt) {
    __shared__ float degT[HT_SIZE];
    __shared__ int   cntT[HT_SIZE];
    int tile = blockIdx.x / HT_BPT;
    int sub  = blockIdx.x % HT_BPT;
    int lo   = tile << HT_BITS;
    int t = threadIdx.x;
    for (int i = t; i < HT_SIZE; i += 256) { degT[i] = 0.f; cntT[i] = 0; }
    __syncthreads();
    const int per = (EE + HT_BPT - 1) / HT_BPT;   // 25000
    int e0 = sub * per;
    int e1 = e0 + per; if (e1 > EE) e1 = EE;
    for (int e = e0 + t; e < e1; e += 256) {
        int s = src[e], d = dst[e];
        unsigned int ls = (unsigned int)(s - lo);
        unsigned int ld = (unsigned int)(d - lo);
        if (ls < HT_SIZE) atomicAdd(&degT[ls], ew[e]);
        if (ld < HT_SIZE) atomicAdd(&cntT[ld], 1);
    }
    __syncthreads();
    float* pd = part_deg + (size_t)blockIdx.x * HT_SIZE;
    int*   pc = part_cnt + (size_t)blockIdx.x * HT_SIZE;
    for (int i = t; i < HT_SIZE; i += 256) { pd[i] = degT[i]; pc[i] = cntT[i]; }
}

// ------------- reduce partials -> deg, cntI; zero cursor -------------
__global__ __launch_bounds__(256) void k_reduce(const float* __restrict__ part_deg,
                                                const int* __restrict__ part_cnt,
                                                float* __restrict__ deg,
                                                int* __restrict__ cntI,
                                                int* __restrict__ cursor) {
    int n = blockIdx.x * 256 + threadIdx.x;
    if (n >= NN) return;
    int tile = n >> HT_BITS, local = n & (HT_SIZE - 1);
    const float* pd = part_deg + ((size_t)tile * HT_BPT) * HT_SIZE + local;
    const int*   pc = part_cnt + ((size_t)tile * HT_BPT) * HT_SIZE + local;
    float sd = 0.f; int sc = 0;
#pragma unroll
    for (int b = 0; b < HT_BPT; ++b) {
        sd += pd[(size_t)b * HT_SIZE];
        sc += pc[(size_t)b * HT_SIZE];
    }
    deg[n] = sd; cntI[n] = sc; cursor[n] = 0;
}

// ------------- 3-phase device-wide exclusive scan of cntI -> rowstart -------------
__global__ __launch_bounds__(256) void k_scan_part(const int* __restrict__ cntI,
                                                   int* __restrict__ blocksum) {
    __shared__ int wsum[4];
    int t = threadIdx.x;
    int base = blockIdx.x * 1024 + t * 4;
    int s = 0;
#pragma unroll
    for (int j = 0; j < 4; ++j) { int i = base + j; if (i < NN) s += cntI[i]; }
#pragma unroll
    for (int off = 32; off > 0; off >>= 1) s += __shfl_down(s, off, 64);
    if ((t & 63) == 0) wsum[t >> 6] = s;
    __syncthreads();
    if (t == 0) blocksum[blockIdx.x] = wsum[0] + wsum[1] + wsum[2] + wsum[3];
}

__global__ __launch_bounds__(64) void k_scan_mid(const int* __restrict__ blocksum,
                                                 int* __restrict__ blockoff,
                                                 int* __restrict__ rowstart) {
    int t = threadIdx.x;
    int v = (t < SBLK) ? blocksum[t] : 0;
    int incl = v;
#pragma unroll
    for (int off = 1; off < 64; off <<= 1) {
        int u = __shfl_up(incl, off, 64);
        if (t >= off) incl += u;
    }
    if (t < SBLK) blockoff[t] = incl - v;
    if (t == 63) rowstart[NN] = incl;
}

__global__ __launch_bounds__(256) void k_scan_final(const int* __restrict__ cntI,
                                                    const int* __restrict__ blockoff,
                                                    int* __restrict__ rowstart) {
    __shared__ int wtot[4];
    int t = threadIdx.x, lane = t & 63, wave = t >> 6;
    int base = blockIdx.x * 1024 + t * 4;
    int v[4]; int s = 0;
#pragma unroll
    for (int j = 0; j < 4; ++j) { int i = base + j; v[j] = (i < NN) ? cntI[i] : 0; s += v[j]; }
    int incl = s;
#pragma unroll
    for (int off = 1; off < 64; off <<= 1) {
        int u = __shfl_up(incl, off, 64);
        if (lane >= off) incl += u;
    }
    if (lane == 63) wtot[wave] = incl;
    __syncthreads();
    int wpre = 0;
    for (int wv = 0; wv < wave; ++wv) wpre += wtot[wv];
    int run = blockoff[blockIdx.x] + wpre + (incl - s);
#pragma unroll
    for (int j = 0; j < 4; ++j) {
        int i = base + j;
        if (i < NN) rowstart[i] = run;
        run += v[j];
    }
}

// ------------- bucket edges by dst: es[pos]=src, wu[pos]=(w, dis_s*w) -------------
__global__ void k_bucket(const int* __restrict__ src, const int* __restrict__ dst,
                         const float* __restrict__ ew, const float* __restrict__ deg,
                         const int* __restrict__ rowstart, int* __restrict__ cursor,
                         int* __restrict__ es, float2* __restrict__ wu) {
    int e = blockIdx.x * blockDim.x + threadIdx.x;
    if (e >= EE) return;
    int s = src[e], d = dst[e];
    float w = ew[e];
    float degs = deg[s];
    float dis_s = degs > 0.f ? rsqrtf(degs) : 0.f;
    int pos = rowstart[d] + atomicAdd(&cursor[d], 1);
    es[pos] = s;
    wu[pos] = make_float2(w, dis_s * w);
}

// ------------- xh = x @ Wp^T + bp (bf16 MFMA) → xh16; also copies x → out (his) -------------
__global__ __launch_bounds__(256) void k_xh(const float* __restrict__ x,
                                            const unsigned short* __restrict__ Pp,
                                            const float* __restrict__ bp,
                                            unsigned short* __restrict__ xh16,
                                            float* __restrict__ his) {
    int wave = threadIdx.x >> 6, l = threadIdx.x & 63;
    int n0 = blockIdx.x * 64 + wave * 16;
    int m = l & 15, q = l >> 4;
    int nodeA = n0 + m;
    bool av = nodeA < NN;
    int na = av ? nodeA : 0;
    floatx4 acc[8];
#pragma unroll
    for (int ct = 0; ct < 8; ++ct) acc[ct] = (floatx4)(0.f);
#pragma unroll
    for (int kc = 0; kc < 4; ++kc) {
        const float* ap = x + (size_t)na * 128 + kc * 32 + q * 8;
        float4 f0 = av ? *(const float4*)ap       : make_float4(0, 0, 0, 0);
        float4 f1 = av ? *(const float4*)(ap + 4) : make_float4(0, 0, 0, 0);
        if (av) {   // fused his = x copy (each element loaded exactly once)
            float* hp = his + (size_t)nodeA * 128 + kc * 32 + q * 8;
            *(float4*)hp       = f0;
            *(float4*)(hp + 4) = f1;
        }
        short8 a;
        a[0] = f2bf(f0.x); a[1] = f2bf(f0.y); a[2] = f2bf(f0.z); a[3] = f2bf(f0.w);
        a[4] = f2bf(f1.x); a[5] = f2bf(f1.y); a[6] = f2bf(f1.z); a[7] = f2bf(f1.w);
#pragma unroll
        for (int ct = 0; ct < 8; ++ct) {
            short8 b = *(const short8*)(Pp + ((kc * 8 + ct) << 9) + l * 8);
            acc[ct] = __builtin_amdgcn_mfma_f32_16x16x32_bf16(a, b, acc[ct], 0, 0, 0);
        }
    }
#pragma unroll
    for (int ct = 0; ct < 8; ++ct) {
        int col = ct * 16 + m;
        float bias = bp[col];
#pragma unroll
        for (int r = 0; r < 4; ++r) {
            int node = n0 + q * 4 + r;
            if (node < NN) xh16[(size_t)node * 128 + col] = f2bf(acc[ct][r] + bias);
        }
    }
}

// ------------- per-dst gather on bf16 xh: Tx1, mean → bf16 -------------
__global__ __launch_bounds__(256) void k_gather(const int* __restrict__ rowstart,
                                                const int* __restrict__ es,
                                                const float2* __restrict__ wu,
                                                const float* __restrict__ deg,
                                                const unsigned short* __restrict__ xh16,
                                                unsigned int* __restrict__ tx16,
                                                unsigned int* __restrict__ mn16) {
    int wave = threadIdx.x >> 6, l = threadIdx.x & 63;
    int n = blockIdx.x * 4 + wave;
    if (n >= NN) return;
    int lo = rowstart[n], hi = rowstart[n + 1];
    float at0 = 0.f, at1 = 0.f, am0 = 0.f, am1 = 0.f;
    int e = lo;
    for (; e + 1 < hi; e += 2) {
        int s0 = es[e], s1 = es[e + 1];
        float2 p0 = wu[e], p1 = wu[e + 1];
        unsigned int v0 = *(const unsigned int*)(xh16 + (size_t)s0 * 128 + l * 2);
        unsigned int v1 = *(const unsigned int*)(xh16 + (size_t)s1 * 128 + l * 2);
        float a0 = bf2f(v0 & 0xffff), a1 = bf2f(v0 >> 16);
        float b0 = bf2f(v1 & 0xffff), b1 = bf2f(v1 >> 16);
        am0 = fmaf(p0.x, a0, am0); am1 = fmaf(p0.x, a1, am1);
        at0 = fmaf(p0.y, a0, at0); at1 = fmaf(p0.y, a1, at1);
        am0 = fmaf(p1.x, b0, am0); am1 = fmaf(p1.x, b1, am1);
        at0 = fmaf(p1.y, b0, at0); at1 = fmaf(p1.y, b1, at1);
    }
    if (e < hi) {
        int s0 = es[e];
        float2 p0 = wu[e];
        unsigned int v0 = *(const unsigned int*)(xh16 + (size_t)s0 * 128 + l * 2);
        float a0 = bf2f(v0 & 0xffff), a1 = bf2f(v0 >> 16);
        am0 = fmaf(p0.x, a0, am0); am1 = fmaf(p0.x, a1, am1);
        at0 = fmaf(p0.y, a0, at0); at1 = fmaf(p0.y, a1, at1);
    }
    float dd = deg[n];
    float dis_d = dd > 0.f ? rsqrtf(dd) : 0.f;
    int c = hi - lo;
    float ic = 1.f / (float)(c > 0 ? c : 1);
    unsigned int tpack = (unsigned int)f2bf(-dis_d * at0) |
                         ((unsigned int)f2bf(-dis_d * at1) << 16);
    unsigned int mpack = (unsigned int)f2bf(am0 * ic) |
                         ((unsigned int)f2bf(am1 * ic) << 16);
    tx16[(size_t)n * 64 + l] = tpack;
    mn16[(size_t)n * 64 + l] = mpack;
}

// ------------- fused epilogue (bf16 MFMA): o1, o2, s, o3 -------------
__global__ __launch_bounds__(256) void k_fused(const unsigned short* __restrict__ xh16,
                                               const unsigned short* __restrict__ tx16,
                                               const unsigned short* __restrict__ mn16,
                                               const unsigned short* __restrict__ Pc0,
                                               const unsigned short* __restrict__ Pc1,
                                               const unsigned short* __restrict__ Prel,
                                               const unsigned short* __restrict__ Proot,
                                               const unsigned short* __restrict__ Pl,
                                               const float* __restrict__ bc,
                                               const float* __restrict__ brel,
                                               const float* __restrict__ bl,
                                               float* __restrict__ out) {
    __shared__ __align__(16) unsigned short sS[4][16][136];
    int wave = threadIdx.x >> 6, l = threadIdx.x & 63;
    int n0 = blockIdx.x * 64 + wave * 16;
    int m = l & 15, q = l >> 4;
    int nodeA = n0 + m;
    bool av = nodeA < NN;
    size_t ra = (size_t)(av ? nodeA : 0) * 128 + q * 8;
    floatx4 acc1[8], acc2[8];
#pragma unroll
    for (int ct = 0; ct < 8; ++ct) { acc1[ct] = (floatx4)(0.f); acc2[ct] = (floatx4)(0.f); }
#pragma unroll
    for (int kc = 0; kc < 4; ++kc) {
        short8 a_xh = *(const short8*)(xh16 + ra + kc * 32);
        short8 a_tx = *(const short8*)(tx16 + ra + kc * 32);
        short8 a_mn = *(const short8*)(mn16 + ra + kc * 32);
#pragma unroll
        for (int ct = 0; ct < 8; ++ct) {
            int po = ((kc * 8 + ct) << 9) + l * 8;
            short8 b0 = *(const short8*)(Pc0 + po);
            short8 b1 = *(const short8*)(Pc1 + po);
            short8 b2 = *(const short8*)(Prel + po);
            short8 b3 = *(const short8*)(Proot + po);
            acc1[ct] = __builtin_amdgcn_mfma_f32_16x16x32_bf16(a_xh, b0, acc1[ct], 0, 0, 0);
            acc1[ct] = __builtin_amdgcn_mfma_f32_16x16x32_bf16(a_tx, b1, acc1[ct], 0, 0, 0);
            acc2[ct] = __builtin_amdgcn_mfma_f32_16x16x32_bf16(a_mn, b2, acc2[ct], 0, 0, 0);
            acc2[ct] = __builtin_amdgcn_mfma_f32_16x16x32_bf16(a_xh, b3, acc2[ct], 0, 0, 0);
        }
    }
#pragma unroll
    for (int ct = 0; ct < 8; ++ct) {
        int col = ct * 16 + m;
        float b1v = bc[col], b2v = brel[col];
#pragma unroll
        for (int r = 0; r < 4; ++r) {
            float u = leaky(acc1[ct][r] + b1v) + leaky(acc2[ct][r] + b2v);
            sS[wave][q * 4 + r][col] = f2bf(u);
        }
    }
    floatx4 acc3[8];
#pragma unroll
    for (int ct = 0; ct < 8; ++ct) acc3[ct] = (floatx4)(0.f);
#pragma unroll
    for (int kc = 0; kc < 4; ++kc) {
        short8 a_s = *(const short8*)&sS[wave][m][kc * 32 + q * 8];
#pragma unroll
        for (int ct = 0; ct < 8; ++ct) {
            short8 b = *(const short8*)(Pl + ((kc * 8 + ct) << 9) + l * 8);
            acc3[ct] = __builtin_amdgcn_mfma_f32_16x16x32_bf16(a_s, b, acc3[ct], 0, 0, 0);
        }
    }
#pragma unroll
    for (int ct = 0; ct < 8; ++ct) {
        int col = ct * 16 + m;
        float bv = bl[col];
#pragma unroll
        for (int r = 0; r < 4; ++r) {
            int node = n0 + q * 4 + r;
            if (node < NN) out[(size_t)node * 128 + col] = acc3[ct][r] + bv;
        }
    }
}

extern "C" void kernel_launch(void* const* d_in, const int* in_sizes, int n_in,
                              void* d_out, int out_size, void* d_ws, size_t ws_size,
                              hipStream_t stream) {
    const float* x    = (const float*)d_in[1];
    const int*   ei   = (const int*)d_in[2];
    const float* ew   = (const float*)d_in[3];
    const float* Wp   = (const float*)d_in[4];
    const float* bp   = (const float*)d_in[5];
    const float* Wc0  = (const float*)d_in[6];
    const float* Wc1  = (const float*)d_in[7];
    const float* bc   = (const float*)d_in[8];
    const float* Wrel = (const float*)d_in[9];
    const float* brel = (const float*)d_in[10];
    const float* Wroot= (const float*)d_in[11];
    const float* Wl   = (const float*)d_in[12];
    const float* bl   = (const float*)d_in[13];
    (void)in_sizes; (void)n_in; (void)out_size; (void)ws_size;
    float* out = (float*)d_out;

    unsigned short* xh16 = (unsigned short*)d_ws;        // NN*128 bf16
    unsigned short* tx16 = xh16 + (size_t)NN * 128;
    unsigned short* mn16 = tx16 + (size_t)NN * 128;
    unsigned short* Pall = mn16 + (size_t)NN * 128;      // 6*16384 bf16
    unsigned short* Pp   = Pall;
    unsigned short* Pc0  = Pall + 1 * 16384;
    unsigned short* Pc1  = Pall + 2 * 16384;
    unsigned short* Prel = Pall + 3 * 16384;
    unsigned short* Proot= Pall + 4 * 16384;
    unsigned short* Pl   = Pall + 5 * 16384;
    float* deg    = (float*)(Pall + 6 * 16384);          // NN
    int*   cntI   = (int*)(deg + NN);                    // NN
    int*   cursor = cntI + NN;                           // NN
    int*   rowstart = cursor + NN;                       // NN+1 (+1 pad)
    int*   es     = rowstart + NN + 2;                   // EE
    float2* wu    = (float2*)(es + EE);                  // EE (8B aligned)
    int*   blocksum = (int*)(wu + EE);                   // SBLK
    int*   blockoff = blocksum + SBLK + 1;               // SBLK
    float* part_deg = (float*)(blockoff + SBLK + 1);     // HT_TILES*HT_BPT*HT_SIZE
    int*   part_cnt = (int*)(part_deg + (size_t)HT_TILES * HT_BPT * HT_SIZE);

    const int* srcI = ei;
    const int* dstI = ei + EE;

    k_pack<<<(6 * 16384 + 255) / 256, 256, 0, stream>>>(
        Wp, Wc0, Wc1, Wrel, Wroot, Wl, Pall);
    k_hist<<<HT_TILES * HT_BPT, 256, 0, stream>>>(srcI, dstI, ew, part_deg, part_cnt);
    k_xh<<<(NN + 63) / 64, 256, 0, stream>>>(x, Pp, bp, xh16, out);
    k_reduce<<<(NN + 255) / 256, 256, 0, stream>>>(part_deg, part_cnt, deg, cntI, cursor);
    k_scan_part<<<SBLK, 256, 0, stream>>>(cntI, blocksum);
    k_scan_mid<<<1, 64, 0, stream>>>(blocksum, blockoff, rowstart);
    k_scan_final<<<SBLK, 256, 0, stream>>>(cntI, blockoff, rowstart);
    k_bucket<<<(EE + 255) / 256, 256, 0, stream>>>(srcI, dstI, ew, deg, rowstart,
                                                   cursor, es, wu);
    k_gather<<<(NN + 3) / 4, 256, 0, stream>>>(rowstart, es, wu, deg, xh16,
                                               (unsigned int*)tx16, (unsigned int*)mn16);
    k_fused<<<(NN + 63) / 64, 256, 0, stream>>>(xh16, tx16, mn16, Pc0, Pc1, Prel,
                                                Proot, Pl, bc, brel, bl,
                                                out + (size_t)NN * 128);
}

// Round 6
// 337.641 us; speedup vs baseline: 1.1358x; 1.1358x over previous
//
#include <hip/hip_runtime.h>

#define NN 50000
#define EE 800000
#define D  128
#define SBLK 49        // ceil(NN/1024) for scan

typedef short short8 __attribute__((ext_vector_type(8)));
typedef float floatx4 __attribute__((ext_vector_type(4)));

__device__ __forceinline__ float leaky(float v) { return v > 0.f ? v : 0.01f * v; }

__device__ __forceinline__ unsigned short f2bf(float f) {
    unsigned int u = __float_as_uint(f);
    u = (u + 0x7fff + ((u >> 16) & 1)) >> 16;     // round-to-nearest-even
    return (unsigned short)u;
}
__device__ __forceinline__ float bf2f(unsigned int h) {
    return __uint_as_float(h << 16);
}

// ---------------- zero scratch ----------------
__global__ void k_zero(float4* __restrict__ p, int n4) {
    int i = blockIdx.x * blockDim.x + threadIdx.x;
    if (i < n4) p[i] = make_float4(0.f, 0.f, 0.f, 0.f);
}

// ------------- pack 6 weight mats into bf16 B-fragment order -------------
__global__ void k_pack(const float* __restrict__ Wp,  const float* __restrict__ Wc0,
                       const float* __restrict__ Wc1, const float* __restrict__ Wrel,
                       const float* __restrict__ Wroot, const float* __restrict__ Wl,
                       unsigned short* __restrict__ Pall) {
    int gid = blockIdx.x * blockDim.x + threadIdx.x;
    if (gid >= 6 * 16384) return;
    int m = gid >> 14;
    int r = gid & 16383;
    int j  = r & 7;
    int l  = (r >> 3) & 63;
    int ct = (r >> 9) & 7;
    int kc = r >> 12;
    int n = ct * 16 + (l & 15);
    int k = kc * 32 + (l >> 4) * 8 + j;
    const float* W = m == 0 ? Wp : m == 1 ? Wc0 : m == 2 ? Wc1
                   : m == 3 ? Wrel : m == 4 ? Wroot : Wl;
    Pall[gid] = f2bf(W[n * 128 + k]);
}

// ------------- deg[src]+=w ; rank[e] = old cnt[dst]++  (single atomic pass) -------------
__global__ void k_degrank(const int* __restrict__ src, const int* __restrict__ dst,
                          const float* __restrict__ ew, float* __restrict__ deg,
                          int* __restrict__ cntI, int* __restrict__ rank) {
    int e = blockIdx.x * blockDim.x + threadIdx.x;
    if (e < EE) {
        atomicAdd(&deg[src[e]], ew[e]);
        rank[e] = atomicAdd(&cntI[dst[e]], 1);
    }
}

// ------------- 3-phase device-wide exclusive scan of cntI -> rowstart -------------
__global__ __launch_bounds__(256) void k_scan_part(const int* __restrict__ cntI,
                                                   int* __restrict__ blocksum) {
    __shared__ int wsum[4];
    int t = threadIdx.x;
    int base = blockIdx.x * 1024 + t * 4;
    int s = 0;
#pragma unroll
    for (int j = 0; j < 4; ++j) { int i = base + j; if (i < NN) s += cntI[i]; }
#pragma unroll
    for (int off = 32; off > 0; off >>= 1) s += __shfl_down(s, off, 64);
    if ((t & 63) == 0) wsum[t >> 6] = s;
    __syncthreads();
    if (t == 0) blocksum[blockIdx.x] = wsum[0] + wsum[1] + wsum[2] + wsum[3];
}

__global__ __launch_bounds__(64) void k_scan_mid(const int* __restrict__ blocksum,
                                                 int* __restrict__ blockoff,
                                                 int* __restrict__ rowstart) {
    int t = threadIdx.x;
    int v = (t < SBLK) ? blocksum[t] : 0;
    int incl = v;
#pragma unroll
    for (int off = 1; off < 64; off <<= 1) {
        int u = __shfl_up(incl, off, 64);
        if (t >= off) incl += u;
    }
    if (t < SBLK) blockoff[t] = incl - v;
    if (t == 63) rowstart[NN] = incl;
}

__global__ __launch_bounds__(256) void k_scan_final(const int* __restrict__ cntI,
                                                    const int* __restrict__ blockoff,
                                                    int* __restrict__ rowstart) {
    __shared__ int wtot[4];
    int t = threadIdx.x, lane = t & 63, wave = t >> 6;
    int base = blockIdx.x * 1024 + t * 4;
    int v[4]; int s = 0;
#pragma unroll
    for (int j = 0; j < 4; ++j) { int i = base + j; v[j] = (i < NN) ? cntI[i] : 0; s += v[j]; }
    int incl = s;
#pragma unroll
    for (int off = 1; off < 64; off <<= 1) {
        int u = __shfl_up(incl, off, 64);
        if (lane >= off) incl += u;
    }
    if (lane == 63) wtot[wave] = incl;
    __syncthreads();
    int wpre = 0;
    for (int wv = 0; wv < wave; ++wv) wpre += wtot[wv];
    int run = blockoff[blockIdx.x] + wpre + (incl - s);
#pragma unroll
    for (int j = 0; j < 4; ++j) {
        int i = base + j;
        if (i < NN) rowstart[i] = run;
        run += v[j];
    }
}

// ------------- bucket edges by dst, NO atomics: rec[pos] = {src, w, dis_s*w, 0} -------------
__global__ void k_bucket(const int* __restrict__ src, const int* __restrict__ dst,
                         const float* __restrict__ ew, const float* __restrict__ deg,
                         const int* __restrict__ rowstart, const int* __restrict__ rank,
                         int4* __restrict__ rec) {
    int e = blockIdx.x * blockDim.x + threadIdx.x;
    if (e >= EE) return;
    int s = src[e], d = dst[e];
    float w = ew[e];
    float degs = deg[s];
    float dis_s = degs > 0.f ? rsqrtf(degs) : 0.f;
    int pos = rowstart[d] + rank[e];
    int4 r;
    r.x = s;
    r.y = __float_as_int(w);
    r.z = __float_as_int(dis_s * w);
    r.w = 0;
    rec[pos] = r;
}

// ------------- xh = x @ Wp^T + bp (bf16 MFMA) → xh16; also copies x → out (his) -------------
__global__ __launch_bounds__(256) void k_xh(const float* __restrict__ x,
                                            const unsigned short* __restrict__ Pp,
                                            const float* __restrict__ bp,
                                            unsigned short* __restrict__ xh16,
                                            float* __restrict__ his) {
    int wave = threadIdx.x >> 6, l = threadIdx.x & 63;
    int n0 = blockIdx.x * 64 + wave * 16;
    int m = l & 15, q = l >> 4;
    int nodeA = n0 + m;
    bool av = nodeA < NN;
    int na = av ? nodeA : 0;
    floatx4 acc[8];
#pragma unroll
    for (int ct = 0; ct < 8; ++ct) acc[ct] = (floatx4)(0.f);
#pragma unroll
    for (int kc = 0; kc < 4; ++kc) {
        const float* ap = x + (size_t)na * 128 + kc * 32 + q * 8;
        float4 f0 = av ? *(const float4*)ap       : make_float4(0, 0, 0, 0);
        float4 f1 = av ? *(const float4*)(ap + 4) : make_float4(0, 0, 0, 0);
        if (av) {   // fused his = x copy
            float* hp = his + (size_t)nodeA * 128 + kc * 32 + q * 8;
            *(float4*)hp       = f0;
            *(float4*)(hp + 4) = f1;
        }
        short8 a;
        a[0] = f2bf(f0.x); a[1] = f2bf(f0.y); a[2] = f2bf(f0.z); a[3] = f2bf(f0.w);
        a[4] = f2bf(f1.x); a[5] = f2bf(f1.y); a[6] = f2bf(f1.z); a[7] = f2bf(f1.w);
#pragma unroll
        for (int ct = 0; ct < 8; ++ct) {
            short8 b = *(const short8*)(Pp + ((kc * 8 + ct) << 9) + l * 8);
            acc[ct] = __builtin_amdgcn_mfma_f32_16x16x32_bf16(a, b, acc[ct], 0, 0, 0);
        }
    }
#pragma unroll
    for (int ct = 0; ct < 8; ++ct) {
        int col = ct * 16 + m;
        float bias = bp[col];
#pragma unroll
        for (int r = 0; r < 4; ++r) {
            int node = n0 + q * 4 + r;
            if (node < NN) xh16[(size_t)node * 128 + col] = f2bf(acc[ct][r] + bias);
        }
    }
}

// ------------- per-dst gather on bf16 xh: Tx1, mean → bf16 -------------
__global__ __launch_bounds__(256) void k_gather(const int* __restrict__ rowstart,
                                                const int4* __restrict__ rec,
                                                const float* __restrict__ deg,
                                                const unsigned short* __restrict__ xh16,
                                                unsigned int* __restrict__ tx16,
                                                unsigned int* __restrict__ mn16) {
    int wave = threadIdx.x >> 6, l = threadIdx.x & 63;
    int n = blockIdx.x * 4 + wave;
    if (n >= NN) return;
    int lo = rowstart[n], hi = rowstart[n + 1];
    float at0 = 0.f, at1 = 0.f, am0 = 0.f, am1 = 0.f;
    int e = lo;
    for (; e + 3 < hi; e += 4) {
        int4 r0 = rec[e], r1 = rec[e + 1], r2 = rec[e + 2], r3 = rec[e + 3];
        unsigned int v0 = *(const unsigned int*)(xh16 + (size_t)r0.x * 128 + l * 2);
        unsigned int v1 = *(const unsigned int*)(xh16 + (size_t)r1.x * 128 + l * 2);
        unsigned int v2 = *(const unsigned int*)(xh16 + (size_t)r2.x * 128 + l * 2);
        unsigned int v3 = *(const unsigned int*)(xh16 + (size_t)r3.x * 128 + l * 2);
        float w0 = __int_as_float(r0.y), u0 = __int_as_float(r0.z);
        float w1 = __int_as_float(r1.y), u1 = __int_as_float(r1.z);
        float w2 = __int_as_float(r2.y), u2 = __int_as_float(r2.z);
        float w3 = __int_as_float(r3.y), u3 = __int_as_float(r3.z);
        float a0 = bf2f(v0 & 0xffff), a1 = bf2f(v0 >> 16);
        float b0 = bf2f(v1 & 0xffff), b1 = bf2f(v1 >> 16);
        float c0 = bf2f(v2 & 0xffff), c1 = bf2f(v2 >> 16);
        float d0 = bf2f(v3 & 0xffff), d1 = bf2f(v3 >> 16);
        am0 = fmaf(w0, a0, am0); am1 = fmaf(w0, a1, am1);
        at0 = fmaf(u0, a0, at0); at1 = fmaf(u0, a1, at1);
        am0 = fmaf(w1, b0, am0); am1 = fmaf(w1, b1, am1);
        at0 = fmaf(u1, b0, at0); at1 = fmaf(u1, b1, at1);
        am0 = fmaf(w2, c0, am0); am1 = fmaf(w2, c1, am1);
        at0 = fmaf(u2, c0, at0); at1 = fmaf(u2, c1, at1);
        am0 = fmaf(w3, d0, am0); am1 = fmaf(w3, d1, am1);
        at0 = fmaf(u3, d0, at0); at1 = fmaf(u3, d1, at1);
    }
    for (; e < hi; ++e) {
        int4 r0 = rec[e];
        unsigned int v0 = *(const unsigned int*)(xh16 + (size_t)r0.x * 128 + l * 2);
        float w0 = __int_as_float(r0.y), u0 = __int_as_float(r0.z);
        float a0 = bf2f(v0 & 0xffff), a1 = bf2f(v0 >> 16);
        am0 = fmaf(w0, a0, am0); am1 = fmaf(w0, a1, am1);
        at0 = fmaf(u0, a0, at0); at1 = fmaf(u0, a1, at1);
    }
    float dd = deg[n];
    float dis_d = dd > 0.f ? rsqrtf(dd) : 0.f;
    int c = hi - lo;
    float ic = 1.f / (float)(c > 0 ? c : 1);
    unsigned int tpack = (unsigned int)f2bf(-dis_d * at0) |
                         ((unsigned int)f2bf(-dis_d * at1) << 16);
    unsigned int mpack = (unsigned int)f2bf(am0 * ic) |
                         ((unsigned int)f2bf(am1 * ic) << 16);
    tx16[(size_t)n * 64 + l] = tpack;
    mn16[(size_t)n * 64 + l] = mpack;
}

// ------------- fused epilogue (bf16 MFMA): o1, o2, s, o3 -------------
__global__ __launch_bounds__(256) void k_fused(const unsigned short* __restrict__ xh16,
                                               const unsigned short* __restrict__ tx16,
                                               const unsigned short* __restrict__ mn16,
                                               const unsigned short* __restrict__ Pc0,
                                               const unsigned short* __restrict__ Pc1,
                                               const unsigned short* __restrict__ Prel,
                                               const unsigned short* __restrict__ Proot,
                                               const unsigned short* __restrict__ Pl,
                                               const float* __restrict__ bc,
                                               const float* __restrict__ brel,
                                               const float* __restrict__ bl,
                                               float* __restrict__ out) {
    __shared__ __align__(16) unsigned short sS[4][16][136];
    int wave = threadIdx.x >> 6, l = threadIdx.x & 63;
    int n0 = blockIdx.x * 64 + wave * 16;
    int m = l & 15, q = l >> 4;
    int nodeA = n0 + m;
    bool av = nodeA < NN;
    size_t ra = (size_t)(av ? nodeA : 0) * 128 + q * 8;
    floatx4 acc1[8], acc2[8];
#pragma unroll
    for (int ct = 0; ct < 8; ++ct) { acc1[ct] = (floatx4)(0.f); acc2[ct] = (floatx4)(0.f); }
#pragma unroll
    for (int kc = 0; kc < 4; ++kc) {
        short8 a_xh = *(const short8*)(xh16 + ra + kc * 32);
        short8 a_tx = *(const short8*)(tx16 + ra + kc * 32);
        short8 a_mn = *(const short8*)(mn16 + ra + kc * 32);
#pragma unroll
        for (int ct = 0; ct < 8; ++ct) {
            int po = ((kc * 8 + ct) << 9) + l * 8;
            short8 b0 = *(const short8*)(Pc0 + po);
            short8 b1 = *(const short8*)(Pc1 + po);
            short8 b2 = *(const short8*)(Prel + po);
            short8 b3 = *(const short8*)(Proot + po);
            acc1[ct] = __builtin_amdgcn_mfma_f32_16x16x32_bf16(a_xh, b0, acc1[ct], 0, 0, 0);
            acc1[ct] = __builtin_amdgcn_mfma_f32_16x16x32_bf16(a_tx, b1, acc1[ct], 0, 0, 0);
            acc2[ct] = __builtin_amdgcn_mfma_f32_16x16x32_bf16(a_mn, b2, acc2[ct], 0, 0, 0);
            acc2[ct] = __builtin_amdgcn_mfma_f32_16x16x32_bf16(a_xh, b3, acc2[ct], 0, 0, 0);
        }
    }
#pragma unroll
    for (int ct = 0; ct < 8; ++ct) {
        int col = ct * 16 + m;
        float b1v = bc[col], b2v = brel[col];
#pragma unroll
        for (int r = 0; r < 4; ++r) {
            float u = leaky(acc1[ct][r] + b1v) + leaky(acc2[ct][r] + b2v);
            sS[wave][q * 4 + r][col] = f2bf(u);
        }
    }
    floatx4 acc3[8];
#pragma unroll
    for (int ct = 0; ct < 8; ++ct) acc3[ct] = (floatx4)(0.f);
#pragma unroll
    for (int kc = 0; kc < 4; ++kc) {
        short8 a_s = *(const short8*)&sS[wave][m][kc * 32 + q * 8];
#pragma unroll
        for (int ct = 0; ct < 8; ++ct) {
            short8 b = *(const short8*)(Pl + ((kc * 8 + ct) << 9) + l * 8);
            acc3[ct] = __builtin_amdgcn_mfma_f32_16x16x32_bf16(a_s, b, acc3[ct], 0, 0, 0);
        }
    }
#pragma unroll
    for (int ct = 0; ct < 8; ++ct) {
        int col = ct * 16 + m;
        float bv = bl[col];
#pragma unroll
        for (int r = 0; r < 4; ++r) {
            int node = n0 + q * 4 + r;
            if (node < NN) out[(size_t)node * 128 + col] = acc3[ct][r] + bv;
        }
    }
}

extern "C" void kernel_launch(void* const* d_in, const int* in_sizes, int n_in,
                              void* d_out, int out_size, void* d_ws, size_t ws_size,
                              hipStream_t stream) {
    const float* x    = (const float*)d_in[1];
    const int*   ei   = (const int*)d_in[2];
    const float* ew   = (const float*)d_in[3];
    const float* Wp   = (const float*)d_in[4];
    const float* bp   = (const float*)d_in[5];
    const float* Wc0  = (const float*)d_in[6];
    const float* Wc1  = (const float*)d_in[7];
    const float* bc   = (const float*)d_in[8];
    const float* Wrel = (const float*)d_in[9];
    const float* brel = (const float*)d_in[10];
    const float* Wroot= (const float*)d_in[11];
    const float* Wl   = (const float*)d_in[12];
    const float* bl   = (const float*)d_in[13];
    (void)in_sizes; (void)n_in; (void)out_size; (void)ws_size;
    float* out = (float*)d_out;

    unsigned short* xh16 = (unsigned short*)d_ws;        // NN*128 bf16
    unsigned short* tx16 = xh16 + (size_t)NN * 128;
    unsigned short* mn16 = tx16 + (size_t)NN * 128;
    unsigned short* Pall = mn16 + (size_t)NN * 128;      // 6*16384 bf16
    unsigned short* Pp   = Pall;
    unsigned short* Pc0  = Pall + 1 * 16384;
    unsigned short* Pc1  = Pall + 2 * 16384;
    unsigned short* Prel = Pall + 3 * 16384;
    unsigned short* Proot= Pall + 4 * 16384;
    unsigned short* Pl   = Pall + 5 * 16384;
    float* deg    = (float*)(Pall + 6 * 16384);          // NN floats
    int*   cntI   = (int*)(deg + NN);                    // NN (zeroed with deg)
    int*   rank   = cntI + NN;                           // EE
    int4*  rec    = (int4*)(rank + EE);                  // EE int4 (offset 16B-aligned)
    int*   rowstart = (int*)(rec + EE);                  // NN+1
    int*   blocksum = rowstart + NN + 2;                 // SBLK
    int*   blockoff = blocksum + SBLK + 1;               // SBLK

    const int* srcI = ei;
    const int* dstI = ei + EE;

    // zero deg + cntI (contiguous 2*NN words = 100000 -> 25000 float4)
    k_zero<<<(25000 + 255) / 256, 256, 0, stream>>>((float4*)deg, 25000);
    k_pack<<<(6 * 16384 + 255) / 256, 256, 0, stream>>>(
        Wp, Wc0, Wc1, Wrel, Wroot, Wl, Pall);
    k_xh<<<(NN + 63) / 64, 256, 0, stream>>>(x, Pp, bp, xh16, out);
    k_degrank<<<(EE + 255) / 256, 256, 0, stream>>>(srcI, dstI, ew, deg, cntI, rank);
    k_scan_part<<<SBLK, 256, 0, stream>>>(cntI, blocksum);
    k_scan_mid<<<1, 64, 0, stream>>>(blocksum, blockoff, rowstart);
    k_scan_final<<<SBLK, 256, 0, stream>>>(cntI, blockoff, rowstart);
    k_bucket<<<(EE + 255) / 256, 256, 0, stream>>>(srcI, dstI, ew, deg, rowstart,
                                                   rank, rec);
    k_gather<<<(NN + 3) / 4, 256, 0, stream>>>(rowstart, rec, deg, xh16,
                                               (unsigned int*)tx16, (unsigned int*)mn16);
    k_fused<<<(NN + 63) / 64, 256, 0, stream>>>(xh16, tx16, mn16, Pc0, Pc1, Prel,
                                                Proot, Pl, bc, brel, bl,
                                                out + (size_t)NN * 128);
}

// Round 8
// 321.943 us; speedup vs baseline: 1.1912x; 1.0488x over previous
//
#include <hip/hip_runtime.h>

#define NN 50000
#define EE 800000
#define D  128
#define SBLK 49        // ceil(NN/1024) for scan
#define ZRB 245        // zero blocks: 62500 float4 / 256
#define PKB 384        // pack blocks: 6*16384/256
#define DRB 1563       // degrank blocks: 1563*512 >= EE (2 edges/thread)
#define XHB 782        // xh blocks: ceil(NN/64)

typedef short short8 __attribute__((ext_vector_type(8)));
typedef float floatx4 __attribute__((ext_vector_type(4)));

__device__ __forceinline__ float leaky(float v) { return v > 0.f ? v : 0.01f * v; }

__device__ __forceinline__ unsigned short f2bf(float f) {
    unsigned int u = __float_as_uint(f);
    u = (u + 0x7fff + ((u >> 16) & 1)) >> 16;     // round-to-nearest-even
    return (unsigned short)u;
}
__device__ __forceinline__ float bf2f(unsigned int h) {
    return __uint_as_float(h << 16);
}

// ------------- phase A: zero(deg4+cntI) ∥ pack weights (independent halves) -------------
__global__ __launch_bounds__(256) void k_pre(
    float4* __restrict__ zp,                 // deg4+cntI region, 62500 float4
    const float* __restrict__ Wp,  const float* __restrict__ Wc0,
    const float* __restrict__ Wc1, const float* __restrict__ Wrel,
    const float* __restrict__ Wroot, const float* __restrict__ Wl,
    unsigned short* __restrict__ Pall) {
    int b = blockIdx.x;
    if (b < ZRB) {
        int i = b * 256 + threadIdx.x;
        if (i < 62500) zp[i] = make_float4(0.f, 0.f, 0.f, 0.f);
    } else {
        int gid = (b - ZRB) * 256 + threadIdx.x;
        int mm = gid >> 14;
        int r = gid & 16383;
        int j  = r & 7;
        int l  = (r >> 3) & 63;
        int ct = (r >> 9) & 7;
        int kc = r >> 12;
        int n = ct * 16 + (l & 15);
        int k = kc * 32 + (l >> 4) * 8 + j;
        const float* W = mm == 0 ? Wp : mm == 1 ? Wc0 : mm == 2 ? Wc1
                       : mm == 3 ? Wrel : mm == 4 ? Wroot : Wl;
        Pall[gid] = f2bf(W[n * 128 + k]);
    }
}

// ------------- phase B: degrank ∥ xh(+his copy)  (Pall read across kernel boundary) -------------
__global__ __launch_bounds__(256) void k_front(
    const int* __restrict__ src, const int* __restrict__ dst,
    const float* __restrict__ ew, float* __restrict__ deg4,
    int* __restrict__ cntI, int* __restrict__ rank,
    const float* __restrict__ x, const float* __restrict__ bp,
    unsigned short* __restrict__ xh16, float* __restrict__ his,
    const unsigned short* __restrict__ Pall) {
    int b = blockIdx.x;
    if (b < DRB) {
        // ---- degrank: deg4[e&3][src]+=w ; rank[e] = cnt[dst]++ ----
        int e0 = b * 512 + threadIdx.x;
#pragma unroll
        for (int j = 0; j < 2; ++j) {
            int e = e0 + j * 256;
            if (e < EE) {
                int s = src[e], d = dst[e];
                atomicAdd(&deg4[(e & 3) * NN + s], ew[e]);
                rank[e] = atomicAdd(&cntI[d], 1);
            }
        }
    } else {
        // ---- xh = x @ Wp^T + bp (bf16 MFMA) + his = x copy ----
        int bb = b - DRB;
        const unsigned short* Pp = Pall;   // slot 0
        int wave = threadIdx.x >> 6, l = threadIdx.x & 63;
        int n0 = bb * 64 + wave * 16;
        int m = l & 15, q = l >> 4;
        int nodeA = n0 + m;
        bool av = nodeA < NN;
        int na = av ? nodeA : 0;
        floatx4 acc[8];
#pragma unroll
        for (int ct = 0; ct < 8; ++ct) acc[ct] = (floatx4)(0.f);
#pragma unroll
        for (int kc = 0; kc < 4; ++kc) {
            const float* ap = x + (size_t)na * 128 + kc * 32 + q * 8;
            float4 f0 = av ? *(const float4*)ap       : make_float4(0, 0, 0, 0);
            float4 f1 = av ? *(const float4*)(ap + 4) : make_float4(0, 0, 0, 0);
            if (av) {
                float* hp = his + (size_t)nodeA * 128 + kc * 32 + q * 8;
                *(float4*)hp       = f0;
                *(float4*)(hp + 4) = f1;
            }
            short8 a;
            a[0] = f2bf(f0.x); a[1] = f2bf(f0.y); a[2] = f2bf(f0.z); a[3] = f2bf(f0.w);
            a[4] = f2bf(f1.x); a[5] = f2bf(f1.y); a[6] = f2bf(f1.z); a[7] = f2bf(f1.w);
#pragma unroll
            for (int ct = 0; ct < 8; ++ct) {
                short8 bfr = *(const short8*)(Pp + ((kc * 8 + ct) << 9) + l * 8);
                acc[ct] = __builtin_amdgcn_mfma_f32_16x16x32_bf16(a, bfr, acc[ct], 0, 0, 0);
            }
        }
#pragma unroll
        for (int ct = 0; ct < 8; ++ct) {
            int col = ct * 16 + m;
            float bias = bp[col];
#pragma unroll
            for (int r = 0; r < 4; ++r) {
                int node = n0 + q * 4 + r;
                if (node < NN) xh16[(size_t)node * 128 + col] = f2bf(acc[ct][r] + bias);
            }
        }
    }
}

// ------------- scan phase 1 + deg4 reduce -> deg -------------
__global__ __launch_bounds__(256) void k_scan_part(const int* __restrict__ cntI,
                                                   const float* __restrict__ deg4,
                                                   int* __restrict__ blocksum,
                                                   float* __restrict__ deg) {
    __shared__ int wsum[4];
    int t = threadIdx.x;
    int base = blockIdx.x * 1024 + t * 4;
    int s = 0;
#pragma unroll
    for (int j = 0; j < 4; ++j) {
        int i = base + j;
        if (i < NN) {
            s += cntI[i];
            deg[i] = deg4[i] + deg4[NN + i] + deg4[2 * NN + i] + deg4[3 * NN + i];
        }
    }
#pragma unroll
    for (int off = 32; off > 0; off >>= 1) s += __shfl_down(s, off, 64);
    if ((t & 63) == 0) wsum[t >> 6] = s;
    __syncthreads();
    if (t == 0) blocksum[blockIdx.x] = wsum[0] + wsum[1] + wsum[2] + wsum[3];
}

__global__ __launch_bounds__(64) void k_scan_mid(const int* __restrict__ blocksum,
                                                 int* __restrict__ blockoff,
                                                 int* __restrict__ rowstart) {
    int t = threadIdx.x;
    int v = (t < SBLK) ? blocksum[t] : 0;
    int incl = v;
#pragma unroll
    for (int off = 1; off < 64; off <<= 1) {
        int u = __shfl_up(incl, off, 64);
        if (t >= off) incl += u;
    }
    if (t < SBLK) blockoff[t] = incl - v;
    if (t == 63) rowstart[NN] = incl;
}

__global__ __launch_bounds__(256) void k_scan_final(const int* __restrict__ cntI,
                                                    const int* __restrict__ blockoff,
                                                    int* __restrict__ rowstart) {
    __shared__ int wtot[4];
    int t = threadIdx.x, lane = t & 63, wave = t >> 6;
    int base = blockIdx.x * 1024 + t * 4;
    int v[4]; int s = 0;
#pragma unroll
    for (int j = 0; j < 4; ++j) { int i = base + j; v[j] = (i < NN) ? cntI[i] : 0; s += v[j]; }
    int incl = s;
#pragma unroll
    for (int off = 1; off < 64; off <<= 1) {
        int u = __shfl_up(incl, off, 64);
        if (lane >= off) incl += u;
    }
    if (lane == 63) wtot[wave] = incl;
    __syncthreads();
    int wpre = 0;
    for (int wv = 0; wv < wave; ++wv) wpre += wtot[wv];
    int run = blockoff[blockIdx.x] + wpre + (incl - s);
#pragma unroll
    for (int j = 0; j < 4; ++j) {
        int i = base + j;
        if (i < NN) rowstart[i] = run;
        run += v[j];
    }
}

// ------------- bucket edges by dst, NO atomics: rec[pos] = {src, w, dis_s*w, 0} -------------
__global__ void k_bucket(const int* __restrict__ src, const int* __restrict__ dst,
                         const float* __restrict__ ew, const float* __restrict__ deg,
                         const int* __restrict__ rowstart, const int* __restrict__ rank,
                         int4* __restrict__ rec) {
    int e = blockIdx.x * blockDim.x + threadIdx.x;
    if (e >= EE) return;
    int s = src[e], d = dst[e];
    float w = ew[e];
    float degs = deg[s];
    float dis_s = degs > 0.f ? rsqrtf(degs) : 0.f;
    int pos = rowstart[d] + rank[e];
    int4 r;
    r.x = s;
    r.y = __float_as_int(w);
    r.z = __float_as_int(dis_s * w);
    r.w = 0;
    rec[pos] = r;
}

// ------------- per-dst gather on bf16 xh: Tx1, mean → bf16 -------------
__global__ __launch_bounds__(256) void k_gather(const int* __restrict__ rowstart,
                                                const int4* __restrict__ rec,
                                                const float* __restrict__ deg,
                                                const unsigned short* __restrict__ xh16,
                                                unsigned int* __restrict__ tx16,
                                                unsigned int* __restrict__ mn16) {
    int wave = threadIdx.x >> 6, l = threadIdx.x & 63;
    int n = blockIdx.x * 4 + wave;
    if (n >= NN) return;
    int lo = rowstart[n], hi = rowstart[n + 1];
    float at0 = 0.f, at1 = 0.f, am0 = 0.f, am1 = 0.f;
    int e = lo;
    for (; e + 3 < hi; e += 4) {
        int4 r0 = rec[e], r1 = rec[e + 1], r2 = rec[e + 2], r3 = rec[e + 3];
        unsigned int v0 = *(const unsigned int*)(xh16 + (size_t)r0.x * 128 + l * 2);
        unsigned int v1 = *(const unsigned int*)(xh16 + (size_t)r1.x * 128 + l * 2);
        unsigned int v2 = *(const unsigned int*)(xh16 + (size_t)r2.x * 128 + l * 2);
        unsigned int v3 = *(const unsigned int*)(xh16 + (size_t)r3.x * 128 + l * 2);
        float w0 = __int_as_float(r0.y), u0 = __int_as_float(r0.z);
        float w1 = __int_as_float(r1.y), u1 = __int_as_float(r1.z);
        float w2 = __int_as_float(r2.y), u2 = __int_as_float(r2.z);
        float w3 = __int_as_float(r3.y), u3 = __int_as_float(r3.z);
        float a0 = bf2f(v0 & 0xffff), a1 = bf2f(v0 >> 16);
        float b0 = bf2f(v1 & 0xffff), b1 = bf2f(v1 >> 16);
        float c0 = bf2f(v2 & 0xffff), c1 = bf2f(v2 >> 16);
        float d0 = bf2f(v3 & 0xffff), d1 = bf2f(v3 >> 16);
        am0 = fmaf(w0, a0, am0); am1 = fmaf(w0, a1, am1);
        at0 = fmaf(u0, a0, at0); at1 = fmaf(u0, a1, at1);
        am0 = fmaf(w1, b0, am0); am1 = fmaf(w1, b1, am1);
        at0 = fmaf(u1, b0, at0); at1 = fmaf(u1, b1, at1);
        am0 = fmaf(w2, c0, am0); am1 = fmaf(w2, c1, am1);
        at0 = fmaf(u2, c0, at0); at1 = fmaf(u2, c1, at1);
        am0 = fmaf(w3, d0, am0); am1 = fmaf(w3, d1, am1);
        at0 = fmaf(u3, d0, at0); at1 = fmaf(u3, d1, at1);
    }
    for (; e < hi; ++e) {
        int4 r0 = rec[e];
        unsigned int v0 = *(const unsigned int*)(xh16 + (size_t)r0.x * 128 + l * 2);
        float w0 = __int_as_float(r0.y), u0 = __int_as_float(r0.z);
        float a0 = bf2f(v0 & 0xffff), a1 = bf2f(v0 >> 16);
        am0 = fmaf(w0, a0, am0); am1 = fmaf(w0, a1, am1);
        at0 = fmaf(u0, a0, at0); at1 = fmaf(u0, a1, at1);
    }
    float dd = deg[n];
    float dis_d = dd > 0.f ? rsqrtf(dd) : 0.f;
    int c = hi - lo;
    float ic = 1.f / (float)(c > 0 ? c : 1);
    unsigned int tpack = (unsigned int)f2bf(-dis_d * at0) |
                         ((unsigned int)f2bf(-dis_d * at1) << 16);
    unsigned int mpack = (unsigned int)f2bf(am0 * ic) |
                         ((unsigned int)f2bf(am1 * ic) << 16);
    tx16[(size_t)n * 64 + l] = tpack;
    mn16[(size_t)n * 64 + l] = mpack;
}

// ------------- fused epilogue (bf16 MFMA): o1, o2, s, o3 -------------
__global__ __launch_bounds__(256) void k_fused(const unsigned short* __restrict__ xh16,
                                               const unsigned short* __restrict__ tx16,
                                               const unsigned short* __restrict__ mn16,
                                               const unsigned short* __restrict__ Pall,
                                               const float* __restrict__ bc,
                                               const float* __restrict__ brel,
                                               const float* __restrict__ bl,
                                               float* __restrict__ out) {
    const unsigned short* Pc0  = Pall + 1 * 16384;
    const unsigned short* Pc1  = Pall + 2 * 16384;
    const unsigned short* Prel = Pall + 3 * 16384;
    const unsigned short* Proot= Pall + 4 * 16384;
    const unsigned short* Pl   = Pall + 5 * 16384;
    __shared__ __align__(16) unsigned short sS[4][16][136];
    int wave = threadIdx.x >> 6, l = threadIdx.x & 63;
    int n0 = blockIdx.x * 64 + wave * 16;
    int m = l & 15, q = l >> 4;
    int nodeA = n0 + m;
    bool av = nodeA < NN;
    size_t ra = (size_t)(av ? nodeA : 0) * 128 + q * 8;
    floatx4 acc1[8], acc2[8];
#pragma unroll
    for (int ct = 0; ct < 8; ++ct) { acc1[ct] = (floatx4)(0.f); acc2[ct] = (floatx4)(0.f); }
#pragma unroll
    for (int kc = 0; kc < 4; ++kc) {
        short8 a_xh = *(const short8*)(xh16 + ra + kc * 32);
        short8 a_tx = *(const short8*)(tx16 + ra + kc * 32);
        short8 a_mn = *(const short8*)(mn16 + ra + kc * 32);
#pragma unroll
        for (int ct = 0; ct < 8; ++ct) {
            int po = ((kc * 8 + ct) << 9) + l * 8;
            short8 b0 = *(const short8*)(Pc0 + po);
            short8 b1 = *(const short8*)(Pc1 + po);
            short8 b2 = *(const short8*)(Prel + po);
            short8 b3 = *(const short8*)(Proot + po);
            acc1[ct] = __builtin_amdgcn_mfma_f32_16x16x32_bf16(a_xh, b0, acc1[ct], 0, 0, 0);
            acc1[ct] = __builtin_amdgcn_mfma_f32_16x16x32_bf16(a_tx, b1, acc1[ct], 0, 0, 0);
            acc2[ct] = __builtin_amdgcn_mfma_f32_16x16x32_bf16(a_mn, b2, acc2[ct], 0, 0, 0);
            acc2[ct] = __builtin_amdgcn_mfma_f32_16x16x32_bf16(a_xh, b3, acc2[ct], 0, 0, 0);
        }
    }
#pragma unroll
    for (int ct = 0; ct < 8; ++ct) {
        int col = ct * 16 + m;
        float b1v = bc[col], b2v = brel[col];
#pragma unroll
        for (int r = 0; r < 4; ++r) {
            float u = leaky(acc1[ct][r] + b1v) + leaky(acc2[ct][r] + b2v);
            sS[wave][q * 4 + r][col] = f2bf(u);
        }
    }
    floatx4 acc3[8];
#pragma unroll
    for (int ct = 0; ct < 8; ++ct) acc3[ct] = (floatx4)(0.f);
#pragma unroll
    for (int kc = 0; kc < 4; ++kc) {
        short8 a_s = *(const short8*)&sS[wave][m][kc * 32 + q * 8];
#pragma unroll
        for (int ct = 0; ct < 8; ++ct) {
            short8 b = *(const short8*)(Pl + ((kc * 8 + ct) << 9) + l * 8);
            acc3[ct] = __builtin_amdgcn_mfma_f32_16x16x32_bf16(a_s, b, acc3[ct], 0, 0, 0);
        }
    }
#pragma unroll
    for (int ct = 0; ct < 8; ++ct) {
        int col = ct * 16 + m;
        float bv = bl[col];
#pragma unroll
        for (int r = 0; r < 4; ++r) {
            int node = n0 + q * 4 + r;
            if (node < NN) out[(size_t)node * 128 + col] = acc3[ct][r] + bv;
        }
    }
}

extern "C" void kernel_launch(void* const* d_in, const int* in_sizes, int n_in,
                              void* d_out, int out_size, void* d_ws, size_t ws_size,
                              hipStream_t stream) {
    const float* x    = (const float*)d_in[1];
    const int*   ei   = (const int*)d_in[2];
    const float* ew   = (const float*)d_in[3];
    const float* Wp   = (const float*)d_in[4];
    const float* bp   = (const float*)d_in[5];
    const float* Wc0  = (const float*)d_in[6];
    const float* Wc1  = (const float*)d_in[7];
    const float* bc   = (const float*)d_in[8];
    const float* Wrel = (const float*)d_in[9];
    const float* brel = (const float*)d_in[10];
    const float* Wroot= (const float*)d_in[11];
    const float* Wl   = (const float*)d_in[12];
    const float* bl   = (const float*)d_in[13];
    (void)in_sizes; (void)n_in; (void)out_size; (void)ws_size;
    float* out = (float*)d_out;

    unsigned short* xh16 = (unsigned short*)d_ws;        // NN*128 bf16
    unsigned short* tx16 = xh16 + (size_t)NN * 128;
    unsigned short* mn16 = tx16 + (size_t)NN * 128;
    unsigned short* Pall = mn16 + (size_t)NN * 128;      // 6*16384 bf16
    float* deg4   = (float*)(Pall + 6 * 16384);          // 4*NN (sharded deg)
    int*   cntI   = (int*)(deg4 + 4 * NN);               // NN (zeroed with deg4)
    int*   rank   = cntI + NN;                           // EE
    int4*  rec    = (int4*)(rank + EE);                  // EE int4 (16B-aligned)
    int*   rowstart = (int*)(rec + EE);                  // NN+1
    int*   blocksum = rowstart + NN + 2;                 // SBLK
    int*   blockoff = blocksum + SBLK + 1;               // SBLK
    float* deg    = (float*)(blockoff + SBLK + 1);       // NN (reduced)

    const int* srcI = ei;
    const int* dstI = ei + EE;

    // phase A: zero(deg4+cntI) ∥ pack weights — both must complete before k_front
    k_pre<<<ZRB + PKB, 256, 0, stream>>>(
        (float4*)deg4, Wp, Wc0, Wc1, Wrel, Wroot, Wl, Pall);
    // phase B: degrank (atomic-latency) ∥ xh+his (MFMA/BW)
    k_front<<<DRB + XHB, 256, 0, stream>>>(
        srcI, dstI, ew, deg4, cntI, rank, x, bp, xh16, out, Pall);
    k_scan_part<<<SBLK, 256, 0, stream>>>(cntI, deg4, blocksum, deg);
    k_scan_mid<<<1, 64, 0, stream>>>(blocksum, blockoff, rowstart);
    k_scan_final<<<SBLK, 256, 0, stream>>>(cntI, blockoff, rowstart);
    k_bucket<<<(EE + 255) / 256, 256, 0, stream>>>(srcI, dstI, ew, deg, rowstart,
                                                   rank, rec);
    k_gather<<<(NN + 3) / 4, 256, 0, stream>>>(rowstart, rec, deg, xh16,
                                               (unsigned int*)tx16, (unsigned int*)mn16);
    k_fused<<<(NN + 63) / 64, 256, 0, stream>>>(xh16, tx16, mn16, Pall,
                                                bc, brel, bl, out + (size_t)NN * 128);
}